// Round 10
// baseline (493.302 us; speedup 1.0000x reference)
//
#include <hip/hip_runtime.h>

// Inputs and output are FP32 (per the reference). Internal GEMM/attention
// compute is bf16 MFMA with fp32 accumulate; bf16 stored as unsigned short.

typedef __attribute__((ext_vector_type(8))) short short8;    // 8 bf16 = 1 MFMA A/B frag
typedef __attribute__((ext_vector_type(4))) short short4v;   // 4 bf16 = 8B vector
typedef __attribute__((ext_vector_type(4))) float floatx4;   // MFMA C/D frag
typedef __attribute__((ext_vector_type(4))) int int4v;

__device__ __forceinline__ float bf2f(unsigned short u) {
    return __uint_as_float(((unsigned int)u) << 16);
}
__device__ __forceinline__ unsigned short f2bf(float f) {
    unsigned int u = __float_as_uint(f);
    u += 0x7FFFu + ((u >> 16) & 1u);   // RNE
    return (unsigned short)(u >> 16);
}
__device__ __forceinline__ int pack2bf(float a, float b) {
    return (int)f2bf(a) | ((int)f2bf(b) << 16);
}
// Single-instruction packed f32->bf16 pair (RNE, matches f2bf).
__device__ __forceinline__ unsigned int cvt_pk_bf16(float lo, float hi) {
    unsigned int r;
    asm("v_cvt_pk_bf16_f32 %0, %1, %2" : "=v"(r) : "v"(lo), "v"(hi));
    return r;
}

// Q pre-scale folds softmax's 1/sqrt(64) AND log2(e): 0.125 * log2(e)
#define Q_PRESCALE 0.18033688011112043f

#if __has_builtin(__builtin_amdgcn_exp2f)
__device__ __forceinline__ float fast_exp2(float x) { return __builtin_amdgcn_exp2f(x); }
#else
__device__ __forceinline__ float fast_exp2(float x) { return __expf(x * 0.6931471805599453f); }
#endif

#if __has_builtin(__builtin_amdgcn_permlane32_swap) && __has_builtin(__builtin_amdgcn_permlane16_swap)
#define HAVE_PERMLANE 1
#else
#define HAVE_PERMLANE 0
#endif

// Async global->LDS, 16 B per lane. LDS dest = wave-uniform base + lane*16.
__device__ __forceinline__ void async16(const unsigned short* g, unsigned short* l) {
    __builtin_amdgcn_global_load_lds(
        (const __attribute__((address_space(1))) unsigned int*)g,
        (__attribute__((address_space(3))) unsigned int*)l, 16, 0, 0);
}

#define BARRIER() do { __builtin_amdgcn_s_barrier(); asm volatile("" ::: "memory"); } while (0)
#define VMCNT(n)  asm volatile("s_waitcnt vmcnt(" #n ")" ::: "memory")
#define LGKM0()   asm volatile("s_waitcnt lgkmcnt(0)" ::: "memory")

// ---------------------------------------------------------------------------
// Merged FP32->BF16 convert: x (8192 blocks) + all 4 weight tensors
// (12288 blocks, contiguous bf16 region [0,24MB) of ws in order
// {qkv_w 6MB | proj_w 2MB | w1 8MB | w2 8MB}). One launch, grid 20480.
// ---------------------------------------------------------------------------
__global__ __launch_bounds__(256)
void cvt_all(const float* __restrict__ x, const float* __restrict__ qkv_w,
             const float* __restrict__ proj_w, const float* __restrict__ w1,
             const float* __restrict__ w2,
             unsigned short* __restrict__ xb, unsigned short* __restrict__ wb) {
    const int b = blockIdx.x;
    const float* src;
    unsigned short* dst;
    size_t doff;
    if (b < 8192) {
        src = x + (size_t)b * 1024; dst = xb; doff = (size_t)b * 1024;
    } else {
        const int wk = b - 8192;
        dst = wb; doff = (size_t)wk * 1024;
        if (wk < 3072)      src = qkv_w  + (size_t)wk * 1024;
        else if (wk < 4096) src = proj_w + (size_t)(wk - 3072) * 1024;
        else if (wk < 8192) src = w1     + (size_t)(wk - 4096) * 1024;
        else                src = w2     + (size_t)(wk - 8192) * 1024;
    }
    const int t4 = threadIdx.x * 4;
    float4 v = *(const float4*)&src[t4];
    short4v o;
    o[0] = (short)f2bf(v.x); o[1] = (short)f2bf(v.y);
    o[2] = (short)f2bf(v.z); o[3] = (short)f2bf(v.w);
    *(short4v*)&dst[doff + t4] = o;
}

// ---------------------------------------------------------------------------
// 128x256-tile 2-phase GEMM, 16x16x32 MFMA, reads-in-phase (best measured
// variant for the big-N shapes: r3-vs-r5 A/B). 8 waves 2Mx4N, wave tile
// 64x64 over 2 N-halves, 96 KiB LDS dbuf (1 block/CU), 3-bit XOR swizzle
// (0 conflicts). Phases:
//   p0 = {read af(8)+b0(4); stage B1(t+1); lgkm0; MFMA nh=0};
//   p1 = {read b1(4); stage A,B0(t+2); lgkm0; MFMA nh=1; vmcnt(4)}.
// Ledger (r2-verified): B1(t) staged p0(t-1), drained vmcnt(4)@p1(t-1);
// A,B0(t+1) staged p1(t-1), drained vmcnt(4)@p1(t); WAR: each region's reads
// complete (lgkm0) >=1 barrier before its re-stage. K-loop unrolled x2.
// Used for qkv (NNT=12) and w1 (NNT=16).
// ---------------------------------------------------------------------------
__global__ __launch_bounds__(512, 2)
void gemm128(const unsigned short* __restrict__ A,
             const unsigned short* __restrict__ W,
             const float* __restrict__ bias,
             const float* __restrict__ prelu,
             unsigned short* __restrict__ C,
             int N, int K, int qcols, int NNT) {
    __shared__ alignas(16) unsigned short lA[2][128 * 64];
    __shared__ alignas(16) unsigned short lB[2][256 * 64];

    const int nwg = gridDim.x;
    const int orig = blockIdx.x;
    const int q8 = nwg >> 3, r8 = nwg & 7, xx = orig & 7, rest = orig >> 3;
    const int wgid = (xx < r8 ? xx * (q8 + 1) : r8 * (q8 + 1) + (xx - r8) * q8) + rest;
    const int mt = wgid / NNT, nt = wgid % NNT;
    const int m0 = mt * 128, n0 = nt * 256;

    const int tid  = threadIdx.x;
    const int lane = tid & 63;
    const int wave = tid >> 6;            // 0..7
    const int lr = lane & 15, lq = lane >> 4;
    const int wrow = (wave >> 2) * 64;    // 2-way M split
    const int wcol = (wave & 3) * 32;     // 4-way N split within each half
    const int srow = lane >> 3;
    const int scol = ((lane & 7) ^ srow) << 3;
    const int kx = lr & 7;

    const int NT = K >> 6;

    floatx4 acc[2][4][2] = {};   // [nh][i][j]
    short8 af[4][2], b0[2][2], b1[2][2];

    auto stA = [&](int d, int tt) {
        #pragma unroll
        for (int it = 0; it < 2; ++it) {
            const int rb = (wave * 2 + it) * 8;
            async16(&A[(size_t)(m0 + rb + srow) * K + tt * 64 + scol], &lA[d][rb * 64]);
        }
    };
    auto stB = [&](int d, int tt, int h) {
        #pragma unroll
        for (int it = 0; it < 2; ++it) {
            const int rb = (wave * 2 + it) * 8;
            async16(&W[(size_t)(n0 + h * 128 + rb + srow) * K + tt * 64 + scol],
                    &lB[d][(h * 128 + rb) * 64]);
        }
    };

#define RD_AF(dd)                                                              \
    _Pragma("unroll") for (int i = 0; i < 4; ++i)                              \
    _Pragma("unroll") for (int s = 0; s < 2; ++s)                              \
        af[i][s] = *(const short8*)&lA[dd][(wrow + i * 16 + lr) * 64 +         \
                                           (((s * 4 + lq) ^ kx) << 3)]
#define RD_B0(dd)                                                              \
    _Pragma("unroll") for (int j = 0; j < 2; ++j)                              \
    _Pragma("unroll") for (int s = 0; s < 2; ++s)                              \
        b0[j][s] = *(const short8*)&lB[dd][(wcol + j * 16 + lr) * 64 +         \
                                           (((s * 4 + lq) ^ kx) << 3)]
#define RD_B1(dd)                                                              \
    _Pragma("unroll") for (int j = 0; j < 2; ++j)                              \
    _Pragma("unroll") for (int s = 0; s < 2; ++s)                              \
        b1[j][s] = *(const short8*)&lB[dd][(128 + wcol + j * 16 + lr) * 64 +   \
                                           (((s * 4 + lq) ^ kx) << 3)]
#define MM128(nh, BB)                                                          \
    _Pragma("unroll") for (int s = 0; s < 2; ++s)                              \
    _Pragma("unroll") for (int i = 0; i < 4; ++i)                              \
    _Pragma("unroll") for (int j = 0; j < 2; ++j)                              \
        acc[nh][i][j] = __builtin_amdgcn_mfma_f32_16x16x32_bf16(               \
            af[i][s], BB[j][s], acc[nh][i][j], 0, 0, 0)

    // Prologue: tile0 {A,B0,B1} + tile1 {A,B0} = 10 loads; wait tile0's 6.
    stA(0, 0); stB(0, 0, 0); stB(0, 0, 1);
    stA(1, 1); stB(1, 1, 0);
    VMCNT(4);
    BARRIER();

    auto tile = [&](int t, int d, int e) {
        // ---- phase 0: read af + b0; stage B1(t+1); MFMA nh=0
        RD_AF(d);
        RD_B0(d);
        if (t + 1 < NT) stB(e, t + 1, 1);
        BARRIER();
        LGKM0();
        __builtin_amdgcn_s_setprio(1);
        MM128(0, b0);
        __builtin_amdgcn_s_setprio(0);
        BARRIER();

        // ---- phase 1: read b1; stage A,B0(t+2); MFMA nh=1; boundary vmcnt
        RD_B1(d);
        if (t + 2 < NT) { stA(d, t + 2); stB(d, t + 2, 0); }
        BARRIER();
        LGKM0();
        __builtin_amdgcn_s_setprio(1);
        MM128(1, b1);
        __builtin_amdgcn_s_setprio(0);
        if (t + 2 < NT)      { VMCNT(4); }   // B1(t+1),A,B0(t+1) landed
        else if (t + 1 < NT) { VMCNT(0); }
        BARRIER();
    };

    for (int t = 0; t < NT; t += 2) {   // NT even (K = 1024)
        tile(t, 0, 1);
        tile(t + 1, 1, 0);
    }

#undef RD_AF
#undef RD_B0
#undef RD_B1
#undef MM128

    // Epilogue.
    const bool hasb = (bias != nullptr);
    const bool hasp = (prelu != nullptr);
    const float slope = hasp ? prelu[0] : 0.f;
    #pragma unroll
    for (int nh = 0; nh < 2; ++nh)
        #pragma unroll
        for (int j = 0; j < 2; ++j) {
            const int gc = n0 + nh * 128 + wcol + j * 16 + lr;
            const float bv = hasb ? bias[gc] : 0.f;
            const float cs = (gc < qcols) ? Q_PRESCALE : 1.f;
            #pragma unroll
            for (int i = 0; i < 4; ++i) {
                const int gr = m0 + wrow + i * 16 + lq * 4;
                #pragma unroll
                for (int r = 0; r < 4; ++r) {
                    float v = acc[nh][i][j][r] + bv;
                    if (hasp && v < 0.f) v *= slope;
                    C[(size_t)(gr + r) * N + gc] = f2bf(v * cs);
                }
            }
        }
}

// ---------------------------------------------------------------------------
// 128x128-tile 2-phase GEMM, 4 waves (256 threads, 2x2), 64 KiB LDS dbuf ->
// TWO blocks per CU. Absorption hypothesis: all prior GEMMs run 1 block/CU,
// so every barrier/vmcnt stall is dead time; 2 independent blocks let the CU
// scheduler fill stalls with the other block's waves (m114 co-scheduling,
// m97-lineage 3-block configs hit 874-912 TF). Same proven 2-phase counted
// schedule + 3-bit XOR swizzle. Wave tile 64x64; per phase 16 MFMA.
// Schedule: p0 = {read af(8)+b0(4); stage A(t+1); bar; lgkm0; MFMA j01; bar}
//           p1 = {read b1(4); stage B(t+1); bar; lgkm0; MFMA j23; vmcnt(0); bar}
// Ledger: stages target buffer e whose reads drained (lgkm0 + barrier) in
// tile t-1; vmcnt(0)+barrier at p1-end makes A,B(t+1) visible to all waves
// before p0(t+1) reads (loads in flight ~1-2 phases; stall absorbed by the
// co-resident block). Used for proj and w2 (N=1024 -> grid 512 = 2.0/CU).
// ---------------------------------------------------------------------------
__global__ __launch_bounds__(256, 2)
void gemm_sq(const unsigned short* __restrict__ A,
             const unsigned short* __restrict__ W,
             const float* __restrict__ bias,
             const float* __restrict__ prelu,
             unsigned short* __restrict__ C,
             int N, int K, int qcols, int NNT) {
    __shared__ alignas(16) unsigned short lA[2][128 * 64];
    __shared__ alignas(16) unsigned short lB[2][128 * 64];

    const int nwg = gridDim.x;
    const int orig = blockIdx.x;
    const int q8 = nwg >> 3, r8 = nwg & 7, xx = orig & 7, rest = orig >> 3;
    const int wgid = (xx < r8 ? xx * (q8 + 1) : r8 * (q8 + 1) + (xx - r8) * q8) + rest;
    const int mt = wgid / NNT, nt = wgid % NNT;
    const int m0 = mt * 128, n0 = nt * 128;

    const int tid  = threadIdx.x;
    const int lane = tid & 63;
    const int wave = tid >> 6;            // 0..3
    const int lr = lane & 15, lq = lane >> 4;
    const int wrow = (wave >> 1) * 64;    // 2-way M split
    const int wcol = (wave & 1) * 64;     // 2-way N split
    const int srow = lane >> 3;           // 0..7
    const int scol = ((lane & 7) ^ srow) << 3;
    const int kx = lr & 7;

    const int NT = K >> 6;

    floatx4 acc[4][4] = {};   // [i][j], wave tile 64x64
    short8 af[4][2], b0[2][2], b1[2][2];

    auto stA = [&](int d, int tt) {
        #pragma unroll
        for (int it = 0; it < 4; ++it) {
            const int rb = it * 32 + wave * 8;
            async16(&A[(size_t)(m0 + rb + srow) * K + tt * 64 + scol], &lA[d][rb * 64]);
        }
    };
    auto stB = [&](int d, int tt) {
        #pragma unroll
        for (int it = 0; it < 4; ++it) {
            const int rb = it * 32 + wave * 8;
            async16(&W[(size_t)(n0 + rb + srow) * K + tt * 64 + scol], &lB[d][rb * 64]);
        }
    };

#define RD_AF(dd)                                                              \
    _Pragma("unroll") for (int i = 0; i < 4; ++i)                              \
    _Pragma("unroll") for (int s = 0; s < 2; ++s)                              \
        af[i][s] = *(const short8*)&lA[dd][(wrow + i * 16 + lr) * 64 +         \
                                           (((s * 4 + lq) ^ kx) << 3)]
#define RD_B0(dd)                                                              \
    _Pragma("unroll") for (int j = 0; j < 2; ++j)                              \
    _Pragma("unroll") for (int s = 0; s < 2; ++s)                              \
        b0[j][s] = *(const short8*)&lB[dd][(wcol + j * 16 + lr) * 64 +         \
                                           (((s * 4 + lq) ^ kx) << 3)]
#define RD_B1(dd)                                                              \
    _Pragma("unroll") for (int j = 0; j < 2; ++j)                              \
    _Pragma("unroll") for (int s = 0; s < 2; ++s)                              \
        b1[j][s] = *(const short8*)&lB[dd][(wcol + 32 + j * 16 + lr) * 64 +    \
                                           (((s * 4 + lq) ^ kx) << 3)]
#define MMSQ(jb, BB)                                                           \
    _Pragma("unroll") for (int s = 0; s < 2; ++s)                              \
    _Pragma("unroll") for (int i = 0; i < 4; ++i)                              \
    _Pragma("unroll") for (int j = 0; j < 2; ++j)                              \
        acc[i][(jb) + j] = __builtin_amdgcn_mfma_f32_16x16x32_bf16(            \
            af[i][s], BB[j][s], acc[i][(jb) + j], 0, 0, 0)

    // Prologue: stage tile0 fully, drain, barrier.
    stA(0, 0); stB(0, 0);
    VMCNT(0);
    BARRIER();

    auto tile = [&](int t, int d, int e) {
        // ---- phase 0: read af + b0; stage A(t+1); MFMA cols 0-31
        RD_AF(d);
        RD_B0(d);
        if (t + 1 < NT) stA(e, t + 1);
        BARRIER();
        LGKM0();
        __builtin_amdgcn_s_setprio(1);
        MMSQ(0, b0);
        __builtin_amdgcn_s_setprio(0);
        BARRIER();

        // ---- phase 1: read b1; stage B(t+1); MFMA cols 32-63; drain+bar
        RD_B1(d);
        if (t + 1 < NT) stB(e, t + 1);
        BARRIER();
        LGKM0();
        __builtin_amdgcn_s_setprio(1);
        MMSQ(2, b1);
        __builtin_amdgcn_s_setprio(0);
        VMCNT(0);            // A,B(t+1) landed (absorbed by co-resident block)
        BARRIER();
    };

    for (int t = 0; t < NT; t += 2) {   // NT even (K = 1024/4096)
        tile(t, 0, 1);
        tile(t + 1, 1, 0);
    }

#undef RD_AF
#undef RD_B0
#undef RD_B1
#undef MMSQ

    // Epilogue.
    const bool hasb = (bias != nullptr);
    const bool hasp = (prelu != nullptr);
    const float slope = hasp ? prelu[0] : 0.f;
    #pragma unroll
    for (int j = 0; j < 4; ++j) {
        const int gc = n0 + wcol + j * 16 + lr;
        const float bv = hasb ? bias[gc] : 0.f;
        const float cs = (gc < qcols) ? Q_PRESCALE : 1.f;
        #pragma unroll
        for (int i = 0; i < 4; ++i) {
            const int gr = m0 + wrow + i * 16 + lq * 4;
            #pragma unroll
            for (int r = 0; r < 4; ++r) {
                float v = acc[i][j][r] + bv;
                if (hasp && v < 0.f) v *= slope;
                C[(size_t)(gr + r) * N + gc] = f2bf(v * cs);
            }
        }
    }
}

// ---------------------------------------------------------------------------
// V transpose: vt[(bh*64 + d)*2048 + key] = qkv[(b*2048+key)*3072 + 2048 + h*64 + d]
// ---------------------------------------------------------------------------
__global__ __launch_bounds__(256)
void transpose_v(const unsigned short* __restrict__ qkv,
                 unsigned short* __restrict__ vt) {
    const int kt = blockIdx.x;   // key tile 0..31
    const int bh = blockIdx.y;   // 0..63
    const int b = bh >> 4, h = bh & 15;
    __shared__ unsigned short tile[64 * 65];
    for (int t = threadIdx.x; t < 512; t += 256) {
        const int key = t >> 3, c8 = (t & 7) << 3;
        short8 v8 = *(const short8*)&qkv[((size_t)(b * 2048 + kt * 64 + key)) * 3072 +
                                         2048 + h * 64 + c8];
        #pragma unroll
        for (int e = 0; e < 8; ++e)
            tile[key * 65 + c8 + e] = (unsigned short)v8[e];
    }
    __syncthreads();
    for (int t = threadIdx.x; t < 512; t += 256) {
        const int d = t >> 3, k8 = (t & 7) << 3;
        short8 o;
        #pragma unroll
        for (int e = 0; e < 8; ++e)
            o[e] = (short)tile[(k8 + e) * 65 + d];
        *(short8*)&vt[((size_t)bh * 64 + d) * 2048 + kt * 64 + k8] = o;
    }
}

// ---------------------------------------------------------------------------
// Flash attention, S^T formulation, NO-MAX softmax (exp2; log2e folded into
// the Q pre-scale). FOUR WAVES PER BLOCK sharing the staged K/V chunk;
// double-buffered, raw s_barrier + counted `s_waitcnt vmcnt(4)`.
// K/V LDS tiles XOR-swizzled; P redistribution via permlane32/16_swap.
// setprio(1) around both MFMA clusters. Grid 512: id%8 = bh%8 (XCD locality).
// ---------------------------------------------------------------------------
__global__ __launch_bounds__(256, 2)
void attn_kernel(const unsigned short* __restrict__ qkv,
                 const unsigned short* __restrict__ vt,
                 unsigned short* __restrict__ o_attn) {
    const int id = blockIdx.x;
    const int qg = id >> 6;     // 0..7
    const int bh = id & 63;     // 0..63
    const int b = bh >> 4, h = bh & 15;
    const int tid  = threadIdx.x;
    const int lane = tid & 63;
    const int wave = tid >> 6;  // 0..3
    const int lr = lane & 15;
    const int lq = lane >> 4;
    const int q0 = (qg * 4 + wave) * 64;
    const size_t row0 = (size_t)(b * 2048) * 3072;

    __shared__ alignas(16) unsigned short lK[2][64 * 64];   // [key][d] (swizzled)
    __shared__ alignas(16) unsigned short lV[2][64 * 64];   // [d][key] (swizzled)

    // Q fragments (B-operand): [n = q = j*16+lr][k = s*32 + lq*8 + jj]
    short8 qf[4][2];
    #pragma unroll
    for (int j = 0; j < 4; ++j)
        #pragma unroll
        for (int s = 0; s < 2; ++s)
            qf[j][s] = *(const short8*)&qkv[row0 + (size_t)(q0 + j * 16 + lr) * 3072 +
                                            h * 64 + s * 32 + lq * 8];

    floatx4 oacc[4][4] = {};   // [dtile i][qtile j]: d=i*16+lq*4+r, q=j*16+lr
    float l_i[4] = {0.f, 0.f, 0.f, 0.f};

    const int srow = lane >> 3;                        // staging row-within-8
    const int scol = (((lane & 7) ^ srow)) << 3;       // swizzled source chunk
    const int kx = lr & 7;                             // read-side swizzle key

    // Stage one 64-key chunk into buffer bi: this wave's 2 K rows-of-8 + 2 V.
    auto stage = [&](int bi, int kc) {
        #pragma unroll
        for (int it2 = 0; it2 < 2; ++it2) {
            const int it = wave * 2 + it2;
            const int row = it * 8 + srow;            // row&7 == srow
            async16(&qkv[row0 + (size_t)(kc + row) * 3072 + 1024 + h * 64 + scol],
                    &lK[bi][it * 512 + lane * 8]);
            async16(&vt[((size_t)bh * 64 + row) * 2048 + kc + scol],
                    &lV[bi][it * 512 + lane * 8]);
        }
    };

    // Drain Q loads so vmcnt arithmetic below counts only staging loads.
    asm volatile("s_waitcnt vmcnt(0)" ::: "memory");
    stage(0, 0);

    #pragma unroll 1
    for (int c = 0; c < 32; ++c) {
        const int cur = c & 1;
        if (c + 1 < 32) {
            stage(cur ^ 1, (c + 1) * 64);            // issue next chunk's 4 loads
            asm volatile("s_waitcnt vmcnt(4)" ::: "memory");
        } else {
            asm volatile("s_waitcnt vmcnt(0)" ::: "memory");
        }
        __builtin_amdgcn_s_barrier();                // all waves staged `cur`
        asm volatile("" ::: "memory");

        // S^T = K·Q^T
        floatx4 sacc[4][4] = {};   // [keytile i][qtile j]: key=i*16+lq*4+r
        #pragma unroll
        for (int s = 0; s < 2; ++s) {
            short8 kf[4];
            #pragma unroll
            for (int i = 0; i < 4; ++i) {
                const int r = i * 16 + lr;
                kf[i] = *(const short8*)&lK[cur][r * 64 + (((s * 4 + lq) ^ kx) << 3)];
            }
            __builtin_amdgcn_s_setprio(1);
            #pragma unroll
            for (int i = 0; i < 4; ++i)
                #pragma unroll
                for (int j = 0; j < 4; ++j)
                    sacc[i][j] = __builtin_amdgcn_mfma_f32_16x16x32_bf16(
                        kf[i], qf[j][s], sacc[i][j], 0, 0, 0);
            __builtin_amdgcn_s_setprio(0);
        }

        // P = 2^S (log2e pre-folded), packed bf16 pairs via v_cvt_pk_bf16_f32.
        unsigned int pkd[4][4][2];
        #pragma unroll
        for (int i = 0; i < 4; ++i)
            #pragma unroll
            for (int j = 0; j < 4; ++j) {
                const float e0 = fast_exp2(sacc[i][j][0]);
                const float e1 = fast_exp2(sacc[i][j][1]);
                const float e2 = fast_exp2(sacc[i][j][2]);
                const float e3 = fast_exp2(sacc[i][j][3]);
                l_i[j] += (e0 + e1) + (e2 + e3);
                pkd[i][j][0] = cvt_pk_bf16(e0, e1);
                pkd[i][j][1] = cvt_pk_bf16(e2, e3);
            }

        // O^T += V^T·P^T.
        #pragma unroll
        for (int s = 0; s < 2; ++s) {
            short8 vf[4];
            #pragma unroll
            for (int i = 0; i < 4; ++i) {
                const int r = i * 16 + lr;
                vf[i] = *(const short8*)&lV[cur][r * 64 + (((s * 4 + lq) ^ kx) << 3)];
            }
            short8 bq[4];
            #pragma unroll
            for (int j = 0; j < 4; ++j) {
                int4v iv;
#if HAVE_PERMLANE
                auto p0 = __builtin_amdgcn_permlane32_swap(
                    pkd[2 * s][j][0], pkd[2 * s + 1][j][0], false, false);
                auto w0 = __builtin_amdgcn_permlane16_swap(p0[0], p0[1], false, false);
                auto p1 = __builtin_amdgcn_permlane32_swap(
                    pkd[2 * s][j][1], pkd[2 * s + 1][j][1], false, false);
                auto w1 = __builtin_amdgcn_permlane16_swap(p1[0], p1[1], false, false);
                iv[0] = (int)w0[0]; iv[1] = (int)w1[0];
                iv[2] = (int)w0[1]; iv[3] = (int)w1[1];
#else
                const int src0 = lr + ((lq & 1) * 2) * 16;
                const int src1 = src0 + 16;
                const bool hi = (lq >> 1) != 0;
                int a0 = __shfl((int)pkd[2 * s][j][0], src0, 64);
                int c0 = __shfl((int)pkd[2 * s + 1][j][0], src0, 64);
                int a1 = __shfl((int)pkd[2 * s][j][1], src0, 64);
                int c1 = __shfl((int)pkd[2 * s + 1][j][1], src0, 64);
                int a2 = __shfl((int)pkd[2 * s][j][0], src1, 64);
                int c2 = __shfl((int)pkd[2 * s + 1][j][0], src1, 64);
                int a3 = __shfl((int)pkd[2 * s][j][1], src1, 64);
                int c3 = __shfl((int)pkd[2 * s + 1][j][1], src1, 64);
                iv[0] = hi ? c0 : a0;
                iv[1] = hi ? c1 : a1;
                iv[2] = hi ? c2 : a2;
                iv[3] = hi ? c3 : a3;
#endif
                bq[j] = __builtin_bit_cast(short8, iv);
            }
            __builtin_amdgcn_s_setprio(1);
            #pragma unroll
            for (int j = 0; j < 4; ++j)
                #pragma unroll
                for (int i = 0; i < 4; ++i)
                    oacc[i][j] = __builtin_amdgcn_mfma_f32_16x16x32_bf16(
                        vf[i], bq[j], oacc[i][j], 0, 0, 0);
            __builtin_amdgcn_s_setprio(0);
        }

        asm volatile("s_waitcnt lgkmcnt(0)" ::: "memory");
        __builtin_amdgcn_s_barrier();
        asm volatile("" ::: "memory");
    }

    // Epilogue: reduce l across the 4 lq groups, normalize, packed stores.
    #pragma unroll
    for (int j = 0; j < 4; ++j) {
        l_i[j] += __shfl_xor(l_i[j], 16, 64);
        l_i[j] += __shfl_xor(l_i[j], 32, 64);
        const float rl = 1.f / l_i[j];
        const int q = q0 + j * 16 + lr;
        #pragma unroll
        for (int i = 0; i < 4; ++i) {
            int2 pk;
            pk.x = pack2bf(oacc[i][j][0] * rl, oacc[i][j][1] * rl);
            pk.y = pack2bf(oacc[i][j][2] * rl, oacc[i][j][3] * rl);
            *(int2*)&o_attn[((size_t)(b * 2048 + q)) * 1024 + h * 64 + i * 16 + lq * 4] = pk;
        }
    }
}

// ---------------------------------------------------------------------------
// LN1: out_bf16 = LayerNorm(x_fp32 + res_bf16) * g + b   (g,b fp32)
// ---------------------------------------------------------------------------
__global__ __launch_bounds__(256)
void ln_f32_bf16(const float* __restrict__ x,
                 const unsigned short* __restrict__ res,
                 const float* __restrict__ g,
                 const float* __restrict__ bta,
                 unsigned short* __restrict__ out) {
    const int row = blockIdx.x;
    const int t = threadIdx.x;
    const size_t base = (size_t)row * 1024;

    float4 xv = *(const float4*)&x[base + t * 4];
    short4v rv = *(const short4v*)&res[base + t * 4];
    float v[4] = { xv.x + bf2f((unsigned short)rv[0]),
                   xv.y + bf2f((unsigned short)rv[1]),
                   xv.z + bf2f((unsigned short)rv[2]),
                   xv.w + bf2f((unsigned short)rv[3]) };
    float s = 0.f, s2 = 0.f;
    #pragma unroll
    for (int k = 0; k < 4; ++k) { s += v[k]; s2 += v[k] * v[k]; }
    #pragma unroll
    for (int off = 32; off > 0; off >>= 1) {
        s  += __shfl_xor(s, off, 64);
        s2 += __shfl_xor(s2, off, 64);
    }
    __shared__ float red[8];
    const int wave = t >> 6;
    if ((t & 63) == 0) { red[wave] = s; red[4 + wave] = s2; }
    __syncthreads();
    s  = red[0] + red[1] + red[2] + red[3];
    s2 = red[4] + red[5] + red[6] + red[7];
    const float mean = s * (1.f / 1024.f);
    const float var  = fmaxf(s2 * (1.f / 1024.f) - mean * mean, 0.f);
    const float inv  = rsqrtf(var + 1e-5f);

    short4v ov;
    #pragma unroll
    for (int k = 0; k < 4; ++k) {
        int c = t * 4 + k;
        ov[k] = (short)f2bf((v[k] - mean) * inv * g[c] + bta[c]);
    }
    *(short4v*)&out[base + t * 4] = ov;
}

// ---------------------------------------------------------------------------
// LN2: out_fp32 = LayerNorm(x_bf16 + res_bf16) * g + b
// ---------------------------------------------------------------------------
__global__ __launch_bounds__(256)
void ln_bf16_f32(const unsigned short* __restrict__ x,
                 const unsigned short* __restrict__ res,
                 const float* __restrict__ g,
                 const float* __restrict__ bta,
                 float* __restrict__ out) {
    const int row = blockIdx.x;
    const int t = threadIdx.x;
    const size_t base = (size_t)row * 1024;

    short4v xv = *(const short4v*)&x[base + t * 4];
    short4v rv = *(const short4v*)&res[base + t * 4];
    float v[4];
    float s = 0.f, s2 = 0.f;
    #pragma unroll
    for (int k = 0; k < 4; ++k) {
        v[k] = bf2f((unsigned short)xv[k]) + bf2f((unsigned short)rv[k]);
        s += v[k];
        s2 += v[k] * v[k];
    }
    #pragma unroll
    for (int off = 32; off > 0; off >>= 1) {
        s  += __shfl_xor(s, off, 64);
        s2 += __shfl_xor(s2, off, 64);
    }
    __shared__ float red[8];
    const int wave = t >> 6;
    if ((t & 63) == 0) { red[wave] = s; red[4 + wave] = s2; }
    __syncthreads();
    s  = red[0] + red[1] + red[2] + red[3];
    s2 = red[4] + red[5] + red[6] + red[7];
    const float mean = s * (1.f / 1024.f);
    const float var  = fmaxf(s2 * (1.f / 1024.f) - mean * mean, 0.f);
    const float inv  = rsqrtf(var + 1e-5f);

    float4 ov;
    ov.x = (v[0] - mean) * inv * g[t * 4 + 0] + bta[t * 4 + 0];
    ov.y = (v[1] - mean) * inv * g[t * 4 + 1] + bta[t * 4 + 1];
    ov.z = (v[2] - mean) * inv * g[t * 4 + 2] + bta[t * 4 + 2];
    ov.w = (v[3] - mean) * inv * g[t * 4 + 3] + bta[t * 4 + 3];
    *(float4*)&out[base + t * 4] = ov;
}

// ---------------------------------------------------------------------------
extern "C" void kernel_launch(void* const* d_in, const int* in_sizes, int n_in,
                              void* d_out, int out_size, void* d_ws, size_t ws_size,
                              hipStream_t stream) {
    const float* x      = (const float*)d_in[0];
    const float* qkv_w  = (const float*)d_in[1];
    const float* proj_w = (const float*)d_in[2];
    const float* proj_b = (const float*)d_in[3];
    const float* ln1_g  = (const float*)d_in[4];
    const float* ln1_b  = (const float*)d_in[5];
    const float* w1     = (const float*)d_in[6];
    const float* b1     = (const float*)d_in[7];
    const float* prelu  = (const float*)d_in[8];
    const float* w2     = (const float*)d_in[9];
    const float* b2     = (const float*)d_in[10];
    const float* ln2_g  = (const float*)d_in[11];
    const float* ln2_b  = (const float*)d_in[12];
    float* out = (float*)d_out;

    // Workspace (bf16 buffers), peak 120 MB (validated):
    //  [0,24)   weights (qkv 6 | proj 2 | w1 8 | w2 8)  <- cvt_all order
    //  [24,40)  xb -> vt (after qkv GEMM) -> pout (after attn) -> h2
    //  [40,88)  qkvb -> x1b[40,56)       [88,104) oat       h1 = [56,120)
    char* ws = (char*)d_ws;
    const size_t MB = 1024 * 1024;
    unsigned short* wqkvb  = (unsigned short*)(ws);
    unsigned short* wprojb = (unsigned short*)(ws + 6 * MB);
    unsigned short* w1b    = (unsigned short*)(ws + 8 * MB);
    unsigned short* w2b    = (unsigned short*)(ws + 16 * MB);
    unsigned short* xb     = (unsigned short*)(ws + 24 * MB);
    unsigned short* vtb    = (unsigned short*)(ws + 24 * MB);  // alias xb (dead)
    unsigned short* qkvb   = (unsigned short*)(ws + 40 * MB);
    unsigned short* oat    = (unsigned short*)(ws + 88 * MB);
    unsigned short* pout   = (unsigned short*)(ws + 24 * MB);  // alias vt (dead)
    unsigned short* x1b    = (unsigned short*)(ws + 40 * MB);
    unsigned short* h1     = (unsigned short*)(ws + 56 * MB);
    unsigned short* h2     = (unsigned short*)(ws + 24 * MB);

    // 0) fp32 -> bf16 conversions: ONE launch (x + all weights)
    cvt_all<<<20480, 256, 0, stream>>>(x, qkv_w, proj_w, w1, w2,
                                       xb, (unsigned short*)ws);

    // 1) qkv = x @ qkv_w^T  [8192,3072], Q cols pre-scaled 0.125*log2e.
    //    gemm128: grid 64*12 = 768 = 3.0 blocks/CU (exact fill).
    gemm128<<<dim3(64 * 12), 512, 0, stream>>>(xb, wqkvb, nullptr, nullptr,
                                               qkvb, 3072, 1024, 1024, 12);
    // 1b) V transpose -> vt[bh][d][key]  (xb dead)
    transpose_v<<<dim3(32, 64), 256, 0, stream>>>(qkvb, vtb);
    // 2) flash attention -> oat [8192,1024]  (4-wave blocks, shared staging)
    attn_kernel<<<512, 256, 0, stream>>>(qkvb, vtb, oat);
    // 3) proj -> pout (vt dead). gemm_sq: grid 64*8 = 512 = 2.0 blocks/CU.
    gemm_sq<<<dim3(64 * 8), 256, 0, stream>>>(oat, wprojb, proj_b, nullptr,
                                              pout, 1024, 1024, 0, 8);
    // 4) x1b = LN(x + pout)  (qkvb dead)
    ln_f32_bf16<<<8192, 256, 0, stream>>>(x, pout, ln1_g, ln1_b, x1b);
    // 5) h1 = PReLU(x1b @ w1^T + b1)  [8192,4096]. gemm128: grid 64*16 = 1024.
    gemm128<<<dim3(64 * 16), 512, 0, stream>>>(x1b, w1b, b1, prelu,
                                               h1, 4096, 1024, 0, 16);
    // 6) h2 = h1 @ w2^T + b2  [8192,1024]. gemm_sq: grid 512 = 2.0/CU, K=4096.
    gemm_sq<<<dim3(64 * 8), 256, 0, stream>>>(h1, w2b, b2, nullptr,
                                              h2, 1024, 4096, 0, 8);
    // 7) out = LN(x1b + h2)  (fp32 out)
    ln_bf16_f32<<<8192, 256, 0, stream>>>(x1b, h2, ln2_g, ln2_b, out);
}

// Round 11
// 472.568 us; speedup vs baseline: 1.0439x; 1.0439x over previous
//
#include <hip/hip_runtime.h>

// Inputs and output are FP32 (per the reference). Internal GEMM/attention
// compute is bf16 MFMA with fp32 accumulate; bf16 stored as unsigned short.

typedef __attribute__((ext_vector_type(8))) short short8;    // 8 bf16 = 1 MFMA A/B frag
typedef __attribute__((ext_vector_type(4))) short short4v;   // 4 bf16 = 8B vector
typedef __attribute__((ext_vector_type(4))) float floatx4;   // MFMA C/D frag
typedef __attribute__((ext_vector_type(4))) int int4v;

__device__ __forceinline__ float bf2f(unsigned short u) {
    return __uint_as_float(((unsigned int)u) << 16);
}
__device__ __forceinline__ unsigned short f2bf(float f) {
    unsigned int u = __float_as_uint(f);
    u += 0x7FFFu + ((u >> 16) & 1u);   // RNE
    return (unsigned short)(u >> 16);
}
__device__ __forceinline__ int pack2bf(float a, float b) {
    return (int)f2bf(a) | ((int)f2bf(b) << 16);
}
// Single-instruction packed f32->bf16 pair (RNE, matches f2bf).
__device__ __forceinline__ unsigned int cvt_pk_bf16(float lo, float hi) {
    unsigned int r;
    asm("v_cvt_pk_bf16_f32 %0, %1, %2" : "=v"(r) : "v"(lo), "v"(hi));
    return r;
}

// Q pre-scale folds softmax's 1/sqrt(64) AND log2(e): 0.125 * log2(e)
#define Q_PRESCALE 0.18033688011112043f

#if __has_builtin(__builtin_amdgcn_exp2f)
__device__ __forceinline__ float fast_exp2(float x) { return __builtin_amdgcn_exp2f(x); }
#else
__device__ __forceinline__ float fast_exp2(float x) { return __expf(x * 0.6931471805599453f); }
#endif

#if __has_builtin(__builtin_amdgcn_permlane32_swap) && __has_builtin(__builtin_amdgcn_permlane16_swap)
#define HAVE_PERMLANE 1
#else
#define HAVE_PERMLANE 0
#endif

// Async global->LDS, 16 B per lane. LDS dest = wave-uniform base + lane*16.
__device__ __forceinline__ void async16(const unsigned short* g, unsigned short* l) {
    __builtin_amdgcn_global_load_lds(
        (const __attribute__((address_space(1))) unsigned int*)g,
        (__attribute__((address_space(3))) unsigned int*)l, 16, 0, 0);
}

#define BARRIER() do { __builtin_amdgcn_s_barrier(); asm volatile("" ::: "memory"); } while (0)
#define VMCNT(n)  asm volatile("s_waitcnt vmcnt(" #n ")" ::: "memory")
#define LGKM0()   asm volatile("s_waitcnt lgkmcnt(0)" ::: "memory")

// ---------------------------------------------------------------------------
// Merged FP32->BF16 convert: x (8192 blocks) + all 4 weight tensors
// (12288 blocks, contiguous bf16 region [0,24MB) of ws in order
// {qkv_w 6MB | proj_w 2MB | w1 8MB | w2 8MB}). One launch, grid 20480.
// ---------------------------------------------------------------------------
__global__ __launch_bounds__(256)
void cvt_all(const float* __restrict__ x, const float* __restrict__ qkv_w,
             const float* __restrict__ proj_w, const float* __restrict__ w1,
             const float* __restrict__ w2,
             unsigned short* __restrict__ xb, unsigned short* __restrict__ wb) {
    const int b = blockIdx.x;
    const float* src;
    unsigned short* dst;
    size_t doff;
    if (b < 8192) {
        src = x + (size_t)b * 1024; dst = xb; doff = (size_t)b * 1024;
    } else {
        const int wk = b - 8192;
        dst = wb; doff = (size_t)wk * 1024;
        if (wk < 3072)      src = qkv_w  + (size_t)wk * 1024;
        else if (wk < 4096) src = proj_w + (size_t)(wk - 3072) * 1024;
        else if (wk < 8192) src = w1     + (size_t)(wk - 4096) * 1024;
        else                src = w2     + (size_t)(wk - 8192) * 1024;
    }
    const int t4 = threadIdx.x * 4;
    float4 v = *(const float4*)&src[t4];
    short4v o;
    o[0] = (short)f2bf(v.x); o[1] = (short)f2bf(v.y);
    o[2] = (short)f2bf(v.z); o[3] = (short)f2bf(v.w);
    *(short4v*)&dst[doff + t4] = o;
}

// ---------------------------------------------------------------------------
// 256x256-tile 8-phase GEMM, 16x16x32 MFMA, PIPELINED REGISTER READS
// (r5/r8-verified best variant for w1: 90 us, 0 bank conflicts; r10 showed
// gemm128 on w1 regresses to 101 us). BK=64, 8 waves (2M x 4N), 512 thr,
// 128 KiB LDS dbuf, 3-bit XOR chunk swizzle. Fragments read one phase ahead
// (register recycling: b1(t) p0-pre; af1(t) p1-post; af0,b0(t+1) p3-post).
// vmcnt(4) at p2-end guarantees all tile-t+1 staging landed before the
// p3-post reads. K-loop unrolled x2 (literal LDS buffer index; NT even).
// ---------------------------------------------------------------------------
__global__ __launch_bounds__(512, 2)
void gemm256(const unsigned short* __restrict__ A,
             const unsigned short* __restrict__ W,
             const float* __restrict__ bias,   // nullable, len N, fp32
             const float* __restrict__ prelu,  // nullable, scalar, fp32
             unsigned short* __restrict__ C,
             int N, int K, int qcols, int NNT) {
    __shared__ alignas(16) unsigned short lA[2][256 * 64];
    __shared__ alignas(16) unsigned short lB[2][256 * 64];

    // Bijective XCD swizzle (m204), then wgid = mt*NNT + nt.
    const int nwg = gridDim.x;
    const int orig = blockIdx.x;
    const int q8 = nwg >> 3, r8 = nwg & 7, xx = orig & 7, rest = orig >> 3;
    const int wgid = (xx < r8 ? xx * (q8 + 1) : r8 * (q8 + 1) + (xx - r8) * q8) + rest;
    const int mt = wgid / NNT, nt = wgid % NNT;
    const int m0 = mt * 256, n0 = nt * 256;

    const int tid  = threadIdx.x;
    const int lane = tid & 63;
    const int wave = tid >> 6;            // 0..7
    const int lr = lane & 15, lq = lane >> 4;
    const int wrow = (wave >> 2) * 64;    // wave row chunk within each M-half
    const int wcol = (wave & 3) * 32;     // wave col chunk within each N-half
    const int srow = lane >> 3;           // staging row within 8-row chunk
    const int scol = ((lane & 7) ^ srow) << 3;   // inverse-swizzled source col
    const int kx = lr & 7;                       // read-side swizzle key

    const int NT = K >> 6;

    floatx4 acc[2][2][4][2] = {};   // [mh][nh][i][j]
    short8 af[4][2], b0[2][2], b1[2][2];

    auto stA = [&](int d, int tt, int h) {
        #pragma unroll
        for (int it = 0; it < 2; ++it) {
            const int rb = h * 128 + (wave * 2 + it) * 8;
            async16(&A[(size_t)(m0 + rb + srow) * K + tt * 64 + scol], &lA[d][rb * 64]);
        }
    };
    auto stB = [&](int d, int tt, int h) {
        #pragma unroll
        for (int it = 0; it < 2; ++it) {
            const int rb = h * 128 + (wave * 2 + it) * 8;
            async16(&W[(size_t)(n0 + rb + srow) * K + tt * 64 + scol], &lB[d][rb * 64]);
        }
    };

#define RD_AF(dd, half)                                                        \
    _Pragma("unroll") for (int i = 0; i < 4; ++i)                              \
    _Pragma("unroll") for (int s = 0; s < 2; ++s)                              \
        af[i][s] = *(const short8*)&lA[dd][((half) * 128 + wrow + i * 16 + lr) * 64 + \
                                           (((s * 4 + lq) ^ kx) << 3)]
#define RD_B0(dd)                                                              \
    _Pragma("unroll") for (int j = 0; j < 2; ++j)                              \
    _Pragma("unroll") for (int s = 0; s < 2; ++s)                              \
        b0[j][s] = *(const short8*)&lB[dd][(wcol + j * 16 + lr) * 64 +         \
                                           (((s * 4 + lq) ^ kx) << 3)]
#define RD_B1(dd)                                                              \
    _Pragma("unroll") for (int j = 0; j < 2; ++j)                              \
    _Pragma("unroll") for (int s = 0; s < 2; ++s)                              \
        b1[j][s] = *(const short8*)&lB[dd][(128 + wcol + j * 16 + lr) * 64 +   \
                                           (((s * 4 + lq) ^ kx) << 3)]
#define MM256(mh, nh, BB)                                                      \
    _Pragma("unroll") for (int s = 0; s < 2; ++s)                              \
    _Pragma("unroll") for (int i = 0; i < 4; ++i)                              \
    _Pragma("unroll") for (int j = 0; j < 2; ++j)                              \
        acc[mh][nh][i][j] = __builtin_amdgcn_mfma_f32_16x16x32_bf16(           \
            af[i][s], BB[j][s], acc[mh][nh][i][j], 0, 0, 0)

    // Prologue: tile0 all 4 halves + tile1's first 3 = 14 loads; wait tile0,
    // leave tile1's 6 in flight; then pre-read tile0's p0 fragments.
    stA(0, 0, 0); stB(0, 0, 0); stB(0, 0, 1); stA(0, 0, 1);
    stA(1, 1, 0); stB(1, 1, 0); stB(1, 1, 1);
    VMCNT(6);
    BARRIER();
    RD_AF(0, 0);
    RD_B0(0);

    auto tile = [&](int t, int d, int e) {
        // ---- phase 0: read b1(t); stage A1(t+1); MFMA (0,0){af0,b0}
        RD_B1(d);
        if (t + 1 < NT) stA(e, t + 1, 1);
        BARRIER();
        __builtin_amdgcn_s_setprio(1);
        MM256(0, 0, b0);
        __builtin_amdgcn_s_setprio(0);
        BARRIER();

        // ---- phase 1: stage A0(t+2); MFMA (0,1){af0,b1}; then read af1(t)
        if (t + 2 < NT) stA(d, t + 2, 0);
        BARRIER();
        __builtin_amdgcn_s_setprio(1);
        MM256(0, 1, b1);
        __builtin_amdgcn_s_setprio(0);
        RD_AF(d, 1);
        BARRIER();

        // ---- phase 2: stage B0(t+2); MFMA (1,1){af1,b1}; boundary vmcnt
        if (t + 2 < NT) stB(d, t + 2, 0);
        BARRIER();
        __builtin_amdgcn_s_setprio(1);
        MM256(1, 1, b1);
        __builtin_amdgcn_s_setprio(0);
        if (t + 2 < NT)      { VMCNT(4); }   // all t+1 landed; {A0,B0}(t+2) fly
        else if (t + 1 < NT) { VMCNT(0); }
        BARRIER();   // <- cross-wave guarantee point for tile t+1 data

        // ---- phase 3: stage B1(t+2); MFMA (1,0){af1,b0}; pre-read t+1 frags
        if (t + 2 < NT) stB(d, t + 2, 1);
        BARRIER();
        __builtin_amdgcn_s_setprio(1);
        MM256(1, 0, b0);
        __builtin_amdgcn_s_setprio(0);
        if (t + 1 < NT) {
            RD_AF(e, 0);
            RD_B0(e);
        }
        BARRIER();
    };

    for (int t = 0; t < NT; t += 2) {   // NT even (K = 1024)
        tile(t, 0, 1);
        tile(t + 1, 1, 0);
    }

#undef RD_AF
#undef RD_B0
#undef RD_B1
#undef MM256

    // Epilogue: bias / PReLU / Q prescale, bf16 store.
    const bool hasb = (bias != nullptr);
    const bool hasp = (prelu != nullptr);
    const float slope = hasp ? prelu[0] : 0.f;
    #pragma unroll
    for (int mh = 0; mh < 2; ++mh)
        #pragma unroll
        for (int nh = 0; nh < 2; ++nh)
            #pragma unroll
            for (int j = 0; j < 2; ++j) {
                const int gc = n0 + nh * 128 + wcol + j * 16 + lr;
                const float bv = hasb ? bias[gc] : 0.f;
                const float cs = (gc < qcols) ? Q_PRESCALE : 1.f;
                #pragma unroll
                for (int i = 0; i < 4; ++i) {
                    const int gr = m0 + mh * 128 + wrow + i * 16 + lq * 4;
                    #pragma unroll
                    for (int r = 0; r < 4; ++r) {
                        float v = acc[mh][nh][i][j][r] + bv;
                        if (hasp && v < 0.f) v *= slope;
                        C[(size_t)(gr + r) * N + gc] = f2bf(v * cs);
                    }
                }
            }
}

// ---------------------------------------------------------------------------
// 128x128-tile 2-phase GEMM, 4 waves (256 threads, 2x2), 64 KiB LDS dbuf ->
// TWO independent blocks per CU (stall absorption via m114 co-scheduling).
// r10: net positive on proj+w2. This round also takes qkv (grid 1536 =
// 2.0/CU x3 rounds) to isolate gemm_sq's rate on a 48-GFLOP shape.
// Same proven 2-phase counted schedule + 3-bit XOR swizzle; 16 MFMA/phase.
// Schedule: p0 = {read af(8)+b0(4); stage A(t+1); bar; lgkm0; MFMA j01; bar}
//           p1 = {read b1(4); stage B(t+1); bar; lgkm0; MFMA j23; vmcnt(0); bar}
// Ledger: stages target buffer e whose reads drained (lgkm0 + barrier) in
// tile t-1; vmcnt(0)+barrier at p1-end makes A,B(t+1) visible to all waves
// before p0(t+1) reads.
// ---------------------------------------------------------------------------
__global__ __launch_bounds__(256, 2)
void gemm_sq(const unsigned short* __restrict__ A,
             const unsigned short* __restrict__ W,
             const float* __restrict__ bias,
             const float* __restrict__ prelu,
             unsigned short* __restrict__ C,
             int N, int K, int qcols, int NNT) {
    __shared__ alignas(16) unsigned short lA[2][128 * 64];
    __shared__ alignas(16) unsigned short lB[2][128 * 64];

    const int nwg = gridDim.x;
    const int orig = blockIdx.x;
    const int q8 = nwg >> 3, r8 = nwg & 7, xx = orig & 7, rest = orig >> 3;
    const int wgid = (xx < r8 ? xx * (q8 + 1) : r8 * (q8 + 1) + (xx - r8) * q8) + rest;
    const int mt = wgid / NNT, nt = wgid % NNT;
    const int m0 = mt * 128, n0 = nt * 128;

    const int tid  = threadIdx.x;
    const int lane = tid & 63;
    const int wave = tid >> 6;            // 0..3
    const int lr = lane & 15, lq = lane >> 4;
    const int wrow = (wave >> 1) * 64;    // 2-way M split
    const int wcol = (wave & 1) * 64;     // 2-way N split
    const int srow = lane >> 3;           // 0..7
    const int scol = ((lane & 7) ^ srow) << 3;
    const int kx = lr & 7;

    const int NT = K >> 6;

    floatx4 acc[4][4] = {};   // [i][j], wave tile 64x64
    short8 af[4][2], b0[2][2], b1[2][2];

    auto stA = [&](int d, int tt) {
        #pragma unroll
        for (int it = 0; it < 4; ++it) {
            const int rb = it * 32 + wave * 8;
            async16(&A[(size_t)(m0 + rb + srow) * K + tt * 64 + scol], &lA[d][rb * 64]);
        }
    };
    auto stB = [&](int d, int tt) {
        #pragma unroll
        for (int it = 0; it < 4; ++it) {
            const int rb = it * 32 + wave * 8;
            async16(&W[(size_t)(n0 + rb + srow) * K + tt * 64 + scol], &lB[d][rb * 64]);
        }
    };

#define RD_AF(dd)                                                              \
    _Pragma("unroll") for (int i = 0; i < 4; ++i)                              \
    _Pragma("unroll") for (int s = 0; s < 2; ++s)                              \
        af[i][s] = *(const short8*)&lA[dd][(wrow + i * 16 + lr) * 64 +         \
                                           (((s * 4 + lq) ^ kx) << 3)]
#define RD_B0(dd)                                                              \
    _Pragma("unroll") for (int j = 0; j < 2; ++j)                              \
    _Pragma("unroll") for (int s = 0; s < 2; ++s)                              \
        b0[j][s] = *(const short8*)&lB[dd][(wcol + j * 16 + lr) * 64 +         \
                                           (((s * 4 + lq) ^ kx) << 3)]
#define RD_B1(dd)                                                              \
    _Pragma("unroll") for (int j = 0; j < 2; ++j)                              \
    _Pragma("unroll") for (int s = 0; s < 2; ++s)                              \
        b1[j][s] = *(const short8*)&lB[dd][(wcol + 32 + j * 16 + lr) * 64 +    \
                                           (((s * 4 + lq) ^ kx) << 3)]
#define MMSQ(jb, BB)                                                           \
    _Pragma("unroll") for (int s = 0; s < 2; ++s)                              \
    _Pragma("unroll") for (int i = 0; i < 4; ++i)                              \
    _Pragma("unroll") for (int j = 0; j < 2; ++j)                              \
        acc[i][(jb) + j] = __builtin_amdgcn_mfma_f32_16x16x32_bf16(            \
            af[i][s], BB[j][s], acc[i][(jb) + j], 0, 0, 0)

    // Prologue: stage tile0 fully, drain, barrier.
    stA(0, 0); stB(0, 0);
    VMCNT(0);
    BARRIER();

    auto tile = [&](int t, int d, int e) {
        // ---- phase 0: read af + b0; stage A(t+1); MFMA cols 0-31
        RD_AF(d);
        RD_B0(d);
        if (t + 1 < NT) stA(e, t + 1);
        BARRIER();
        LGKM0();
        __builtin_amdgcn_s_setprio(1);
        MMSQ(0, b0);
        __builtin_amdgcn_s_setprio(0);
        BARRIER();

        // ---- phase 1: read b1; stage B(t+1); MFMA cols 32-63; drain+bar
        RD_B1(d);
        if (t + 1 < NT) stB(e, t + 1);
        BARRIER();
        LGKM0();
        __builtin_amdgcn_s_setprio(1);
        MMSQ(2, b1);
        __builtin_amdgcn_s_setprio(0);
        VMCNT(0);            // A,B(t+1) landed (absorbed by co-resident block)
        BARRIER();
    };

    for (int t = 0; t < NT; t += 2) {   // NT even (K = 1024/4096)
        tile(t, 0, 1);
        tile(t + 1, 1, 0);
    }

#undef RD_AF
#undef RD_B0
#undef RD_B1
#undef MMSQ

    // Epilogue.
    const bool hasb = (bias != nullptr);
    const bool hasp = (prelu != nullptr);
    const float slope = hasp ? prelu[0] : 0.f;
    #pragma unroll
    for (int j = 0; j < 4; ++j) {
        const int gc = n0 + wcol + j * 16 + lr;
        const float bv = hasb ? bias[gc] : 0.f;
        const float cs = (gc < qcols) ? Q_PRESCALE : 1.f;
        #pragma unroll
        for (int i = 0; i < 4; ++i) {
            const int gr = m0 + wrow + i * 16 + lq * 4;
            #pragma unroll
            for (int r = 0; r < 4; ++r) {
                float v = acc[i][j][r] + bv;
                if (hasp && v < 0.f) v *= slope;
                C[(size_t)(gr + r) * N + gc] = f2bf(v * cs);
            }
        }
    }
}

// ---------------------------------------------------------------------------
// V transpose: vt[(bh*64 + d)*2048 + key] = qkv[(b*2048+key)*3072 + 2048 + h*64 + d]
// ---------------------------------------------------------------------------
__global__ __launch_bounds__(256)
void transpose_v(const unsigned short* __restrict__ qkv,
                 unsigned short* __restrict__ vt) {
    const int kt = blockIdx.x;   // key tile 0..31
    const int bh = blockIdx.y;   // 0..63
    const int b = bh >> 4, h = bh & 15;
    __shared__ unsigned short tile[64 * 65];
    for (int t = threadIdx.x; t < 512; t += 256) {
        const int key = t >> 3, c8 = (t & 7) << 3;
        short8 v8 = *(const short8*)&qkv[((size_t)(b * 2048 + kt * 64 + key)) * 3072 +
                                         2048 + h * 64 + c8];
        #pragma unroll
        for (int e = 0; e < 8; ++e)
            tile[key * 65 + c8 + e] = (unsigned short)v8[e];
    }
    __syncthreads();
    for (int t = threadIdx.x; t < 512; t += 256) {
        const int d = t >> 3, k8 = (t & 7) << 3;
        short8 o;
        #pragma unroll
        for (int e = 0; e < 8; ++e)
            o[e] = (short)tile[(k8 + e) * 65 + d];
        *(short8*)&vt[((size_t)bh * 64 + d) * 2048 + kt * 64 + k8] = o;
    }
}

// ---------------------------------------------------------------------------
// Flash attention, S^T formulation, NO-MAX softmax (exp2; log2e folded into
// the Q pre-scale). FOUR WAVES PER BLOCK sharing the staged K/V chunk;
// double-buffered, raw s_barrier + counted `s_waitcnt vmcnt(4)`.
// K/V LDS tiles XOR-swizzled; P redistribution via permlane32/16_swap.
// setprio(1) around both MFMA clusters. Grid 512: id%8 = bh%8 (XCD locality).
// ---------------------------------------------------------------------------
__global__ __launch_bounds__(256, 2)
void attn_kernel(const unsigned short* __restrict__ qkv,
                 const unsigned short* __restrict__ vt,
                 unsigned short* __restrict__ o_attn) {
    const int id = blockIdx.x;
    const int qg = id >> 6;     // 0..7
    const int bh = id & 63;     // 0..63
    const int b = bh >> 4, h = bh & 15;
    const int tid  = threadIdx.x;
    const int lane = tid & 63;
    const int wave = tid >> 6;  // 0..3
    const int lr = lane & 15;
    const int lq = lane >> 4;
    const int q0 = (qg * 4 + wave) * 64;
    const size_t row0 = (size_t)(b * 2048) * 3072;

    __shared__ alignas(16) unsigned short lK[2][64 * 64];   // [key][d] (swizzled)
    __shared__ alignas(16) unsigned short lV[2][64 * 64];   // [d][key] (swizzled)

    // Q fragments (B-operand): [n = q = j*16+lr][k = s*32 + lq*8 + jj]
    short8 qf[4][2];
    #pragma unroll
    for (int j = 0; j < 4; ++j)
        #pragma unroll
        for (int s = 0; s < 2; ++s)
            qf[j][s] = *(const short8*)&qkv[row0 + (size_t)(q0 + j * 16 + lr) * 3072 +
                                            h * 64 + s * 32 + lq * 8];

    floatx4 oacc[4][4] = {};   // [dtile i][qtile j]: d=i*16+lq*4+r, q=j*16+lr
    float l_i[4] = {0.f, 0.f, 0.f, 0.f};

    const int srow = lane >> 3;                        // staging row-within-8
    const int scol = (((lane & 7) ^ srow)) << 3;       // swizzled source chunk
    const int kx = lr & 7;                             // read-side swizzle key

    // Stage one 64-key chunk into buffer bi: this wave's 2 K rows-of-8 + 2 V.
    auto stage = [&](int bi, int kc) {
        #pragma unroll
        for (int it2 = 0; it2 < 2; ++it2) {
            const int it = wave * 2 + it2;
            const int row = it * 8 + srow;            // row&7 == srow
            async16(&qkv[row0 + (size_t)(kc + row) * 3072 + 1024 + h * 64 + scol],
                    &lK[bi][it * 512 + lane * 8]);
            async16(&vt[((size_t)bh * 64 + row) * 2048 + kc + scol],
                    &lV[bi][it * 512 + lane * 8]);
        }
    };

    // Drain Q loads so vmcnt arithmetic below counts only staging loads.
    asm volatile("s_waitcnt vmcnt(0)" ::: "memory");
    stage(0, 0);

    #pragma unroll 1
    for (int c = 0; c < 32; ++c) {
        const int cur = c & 1;
        if (c + 1 < 32) {
            stage(cur ^ 1, (c + 1) * 64);            // issue next chunk's 4 loads
            asm volatile("s_waitcnt vmcnt(4)" ::: "memory");
        } else {
            asm volatile("s_waitcnt vmcnt(0)" ::: "memory");
        }
        __builtin_amdgcn_s_barrier();                // all waves staged `cur`
        asm volatile("" ::: "memory");

        // S^T = K·Q^T
        floatx4 sacc[4][4] = {};   // [keytile i][qtile j]: key=i*16+lq*4+r
        #pragma unroll
        for (int s = 0; s < 2; ++s) {
            short8 kf[4];
            #pragma unroll
            for (int i = 0; i < 4; ++i) {
                const int r = i * 16 + lr;
                kf[i] = *(const short8*)&lK[cur][r * 64 + (((s * 4 + lq) ^ kx) << 3)];
            }
            __builtin_amdgcn_s_setprio(1);
            #pragma unroll
            for (int i = 0; i < 4; ++i)
                #pragma unroll
                for (int j = 0; j < 4; ++j)
                    sacc[i][j] = __builtin_amdgcn_mfma_f32_16x16x32_bf16(
                        kf[i], qf[j][s], sacc[i][j], 0, 0, 0);
            __builtin_amdgcn_s_setprio(0);
        }

        // P = 2^S (log2e pre-folded), packed bf16 pairs via v_cvt_pk_bf16_f32.
        unsigned int pkd[4][4][2];
        #pragma unroll
        for (int i = 0; i < 4; ++i)
            #pragma unroll
            for (int j = 0; j < 4; ++j) {
                const float e0 = fast_exp2(sacc[i][j][0]);
                const float e1 = fast_exp2(sacc[i][j][1]);
                const float e2 = fast_exp2(sacc[i][j][2]);
                const float e3 = fast_exp2(sacc[i][j][3]);
                l_i[j] += (e0 + e1) + (e2 + e3);
                pkd[i][j][0] = cvt_pk_bf16(e0, e1);
                pkd[i][j][1] = cvt_pk_bf16(e2, e3);
            }

        // O^T += V^T·P^T.
        #pragma unroll
        for (int s = 0; s < 2; ++s) {
            short8 vf[4];
            #pragma unroll
            for (int i = 0; i < 4; ++i) {
                const int r = i * 16 + lr;
                vf[i] = *(const short8*)&lV[cur][r * 64 + (((s * 4 + lq) ^ kx) << 3)];
            }
            short8 bq[4];
            #pragma unroll
            for (int j = 0; j < 4; ++j) {
                int4v iv;
#if HAVE_PERMLANE
                auto p0 = __builtin_amdgcn_permlane32_swap(
                    pkd[2 * s][j][0], pkd[2 * s + 1][j][0], false, false);
                auto w0 = __builtin_amdgcn_permlane16_swap(p0[0], p0[1], false, false);
                auto p1 = __builtin_amdgcn_permlane32_swap(
                    pkd[2 * s][j][1], pkd[2 * s + 1][j][1], false, false);
                auto w1 = __builtin_amdgcn_permlane16_swap(p1[0], p1[1], false, false);
                iv[0] = (int)w0[0]; iv[1] = (int)w1[0];
                iv[2] = (int)w0[1]; iv[3] = (int)w1[1];
#else
                const int src0 = lr + ((lq & 1) * 2) * 16;
                const int src1 = src0 + 16;
                const bool hi = (lq >> 1) != 0;
                int a0 = __shfl((int)pkd[2 * s][j][0], src0, 64);
                int c0 = __shfl((int)pkd[2 * s + 1][j][0], src0, 64);
                int a1 = __shfl((int)pkd[2 * s][j][1], src0, 64);
                int c1 = __shfl((int)pkd[2 * s + 1][j][1], src0, 64);
                int a2 = __shfl((int)pkd[2 * s][j][0], src1, 64);
                int c2 = __shfl((int)pkd[2 * s + 1][j][0], src1, 64);
                int a3 = __shfl((int)pkd[2 * s][j][1], src1, 64);
                int c3 = __shfl((int)pkd[2 * s + 1][j][1], src1, 64);
                iv[0] = hi ? c0 : a0;
                iv[1] = hi ? c1 : a1;
                iv[2] = hi ? c2 : a2;
                iv[3] = hi ? c3 : a3;
#endif
                bq[j] = __builtin_bit_cast(short8, iv);
            }
            __builtin_amdgcn_s_setprio(1);
            #pragma unroll
            for (int j = 0; j < 4; ++j)
                #pragma unroll
                for (int i = 0; i < 4; ++i)
                    oacc[i][j] = __builtin_amdgcn_mfma_f32_16x16x32_bf16(
                        vf[i], bq[j], oacc[i][j], 0, 0, 0);
            __builtin_amdgcn_s_setprio(0);
        }

        asm volatile("s_waitcnt lgkmcnt(0)" ::: "memory");
        __builtin_amdgcn_s_barrier();
        asm volatile("" ::: "memory");
    }

    // Epilogue: reduce l across the 4 lq groups, normalize, packed stores.
    #pragma unroll
    for (int j = 0; j < 4; ++j) {
        l_i[j] += __shfl_xor(l_i[j], 16, 64);
        l_i[j] += __shfl_xor(l_i[j], 32, 64);
        const float rl = 1.f / l_i[j];
        const int q = q0 + j * 16 + lr;
        #pragma unroll
        for (int i = 0; i < 4; ++i) {
            int2 pk;
            pk.x = pack2bf(oacc[i][j][0] * rl, oacc[i][j][1] * rl);
            pk.y = pack2bf(oacc[i][j][2] * rl, oacc[i][j][3] * rl);
            *(int2*)&o_attn[((size_t)(b * 2048 + q)) * 1024 + h * 64 + i * 16 + lq * 4] = pk;
        }
    }
}

// ---------------------------------------------------------------------------
// LN1: out_bf16 = LayerNorm(x_fp32 + res_bf16) * g + b   (g,b fp32)
// ---------------------------------------------------------------------------
__global__ __launch_bounds__(256)
void ln_f32_bf16(const float* __restrict__ x,
                 const unsigned short* __restrict__ res,
                 const float* __restrict__ g,
                 const float* __restrict__ bta,
                 unsigned short* __restrict__ out) {
    const int row = blockIdx.x;
    const int t = threadIdx.x;
    const size_t base = (size_t)row * 1024;

    float4 xv = *(const float4*)&x[base + t * 4];
    short4v rv = *(const short4v*)&res[base + t * 4];
    float v[4] = { xv.x + bf2f((unsigned short)rv[0]),
                   xv.y + bf2f((unsigned short)rv[1]),
                   xv.z + bf2f((unsigned short)rv[2]),
                   xv.w + bf2f((unsigned short)rv[3]) };
    float s = 0.f, s2 = 0.f;
    #pragma unroll
    for (int k = 0; k < 4; ++k) { s += v[k]; s2 += v[k] * v[k]; }
    #pragma unroll
    for (int off = 32; off > 0; off >>= 1) {
        s  += __shfl_xor(s, off, 64);
        s2 += __shfl_xor(s2, off, 64);
    }
    __shared__ float red[8];
    const int wave = t >> 6;
    if ((t & 63) == 0) { red[wave] = s; red[4 + wave] = s2; }
    __syncthreads();
    s  = red[0] + red[1] + red[2] + red[3];
    s2 = red[4] + red[5] + red[6] + red[7];
    const float mean = s * (1.f / 1024.f);
    const float var  = fmaxf(s2 * (1.f / 1024.f) - mean * mean, 0.f);
    const float inv  = rsqrtf(var + 1e-5f);

    short4v ov;
    #pragma unroll
    for (int k = 0; k < 4; ++k) {
        int c = t * 4 + k;
        ov[k] = (short)f2bf((v[k] - mean) * inv * g[c] + bta[c]);
    }
    *(short4v*)&out[base + t * 4] = ov;
}

// ---------------------------------------------------------------------------
// LN2: out_fp32 = LayerNorm(x_bf16 + res_bf16) * g + b
// ---------------------------------------------------------------------------
__global__ __launch_bounds__(256)
void ln_bf16_f32(const unsigned short* __restrict__ x,
                 const unsigned short* __restrict__ res,
                 const float* __restrict__ g,
                 const float* __restrict__ bta,
                 float* __restrict__ out) {
    const int row = blockIdx.x;
    const int t = threadIdx.x;
    const size_t base = (size_t)row * 1024;

    short4v xv = *(const short4v*)&x[base + t * 4];
    short4v rv = *(const short4v*)&res[base + t * 4];
    float v[4];
    float s = 0.f, s2 = 0.f;
    #pragma unroll
    for (int k = 0; k < 4; ++k) {
        v[k] = bf2f((unsigned short)xv[k]) + bf2f((unsigned short)rv[k]);
        s += v[k];
        s2 += v[k] * v[k];
    }
    #pragma unroll
    for (int off = 32; off > 0; off >>= 1) {
        s  += __shfl_xor(s, off, 64);
        s2 += __shfl_xor(s2, off, 64);
    }
    __shared__ float red[8];
    const int wave = t >> 6;
    if ((t & 63) == 0) { red[wave] = s; red[4 + wave] = s2; }
    __syncthreads();
    s  = red[0] + red[1] + red[2] + red[3];
    s2 = red[4] + red[5] + red[6] + red[7];
    const float mean = s * (1.f / 1024.f);
    const float var  = fmaxf(s2 * (1.f / 1024.f) - mean * mean, 0.f);
    const float inv  = rsqrtf(var + 1e-5f);

    float4 ov;
    ov.x = (v[0] - mean) * inv * g[t * 4 + 0] + bta[t * 4 + 0];
    ov.y = (v[1] - mean) * inv * g[t * 4 + 1] + bta[t * 4 + 1];
    ov.z = (v[2] - mean) * inv * g[t * 4 + 2] + bta[t * 4 + 2];
    ov.w = (v[3] - mean) * inv * g[t * 4 + 3] + bta[t * 4 + 3];
    *(float4*)&out[base + t * 4] = ov;
}

// ---------------------------------------------------------------------------
extern "C" void kernel_launch(void* const* d_in, const int* in_sizes, int n_in,
                              void* d_out, int out_size, void* d_ws, size_t ws_size,
                              hipStream_t stream) {
    const float* x      = (const float*)d_in[0];
    const float* qkv_w  = (const float*)d_in[1];
    const float* proj_w = (const float*)d_in[2];
    const float* proj_b = (const float*)d_in[3];
    const float* ln1_g  = (const float*)d_in[4];
    const float* ln1_b  = (const float*)d_in[5];
    const float* w1     = (const float*)d_in[6];
    const float* b1     = (const float*)d_in[7];
    const float* prelu  = (const float*)d_in[8];
    const float* w2     = (const float*)d_in[9];
    const float* b2     = (const float*)d_in[10];
    const float* ln2_g  = (const float*)d_in[11];
    const float* ln2_b  = (const float*)d_in[12];
    float* out = (float*)d_out;

    // Workspace (bf16 buffers), peak 120 MB (validated):
    //  [0,24)   weights (qkv 6 | proj 2 | w1 8 | w2 8)  <- cvt_all order
    //  [24,40)  xb -> vt (after qkv GEMM) -> pout (after attn) -> h2
    //  [40,88)  qkvb -> x1b[40,56)       [88,104) oat       h1 = [56,120)
    char* ws = (char*)d_ws;
    const size_t MB = 1024 * 1024;
    unsigned short* wqkvb  = (unsigned short*)(ws);
    unsigned short* wprojb = (unsigned short*)(ws + 6 * MB);
    unsigned short* w1b    = (unsigned short*)(ws + 8 * MB);
    unsigned short* w2b    = (unsigned short*)(ws + 16 * MB);
    unsigned short* xb     = (unsigned short*)(ws + 24 * MB);
    unsigned short* vtb    = (unsigned short*)(ws + 24 * MB);  // alias xb (dead)
    unsigned short* qkvb   = (unsigned short*)(ws + 40 * MB);
    unsigned short* oat    = (unsigned short*)(ws + 88 * MB);
    unsigned short* pout   = (unsigned short*)(ws + 24 * MB);  // alias vt (dead)
    unsigned short* x1b    = (unsigned short*)(ws + 40 * MB);
    unsigned short* h1     = (unsigned short*)(ws + 56 * MB);
    unsigned short* h2     = (unsigned short*)(ws + 24 * MB);

    // 0) fp32 -> bf16 conversions: ONE launch (x + all weights)
    cvt_all<<<20480, 256, 0, stream>>>(x, qkv_w, proj_w, w1, w2,
                                       xb, (unsigned short*)ws);

    // 1) qkv = x @ qkv_w^T  [8192,3072], Q cols pre-scaled 0.125*log2e.
    //    gemm_sq: grid 64*24 = 1536 = 2.0 blocks/CU x 3 rounds.
    gemm_sq<<<dim3(64 * 24), 256, 0, stream>>>(xb, wqkvb, nullptr, nullptr,
                                               qkvb, 3072, 1024, 1024, 24);
    // 1b) V transpose -> vt[bh][d][key]  (xb dead)
    transpose_v<<<dim3(32, 64), 256, 0, stream>>>(qkvb, vtb);
    // 2) flash attention -> oat [8192,1024]  (4-wave blocks, shared staging)
    attn_kernel<<<512, 256, 0, stream>>>(qkvb, vtb, oat);
    // 3) proj -> pout (vt dead). gemm_sq: grid 64*8 = 512 = 2.0 blocks/CU.
    gemm_sq<<<dim3(64 * 8), 256, 0, stream>>>(oat, wprojb, proj_b, nullptr,
                                              pout, 1024, 1024, 0, 8);
    // 4) x1b = LN(x + pout)  (qkvb dead)
    ln_f32_bf16<<<8192, 256, 0, stream>>>(x, pout, ln1_g, ln1_b, x1b);
    // 5) h1 = PReLU(x1b @ w1^T + b1)  [8192,4096]. gemm256 (r8-proven 90us):
    //    grid 32*16 = 512 = 2.0/CU.
    gemm256<<<dim3(32 * 16), 512, 0, stream>>>(x1b, w1b, b1, prelu,
                                               h1, 4096, 1024, 0, 16);
    // 6) h2 = h1 @ w2^T + b2  [8192,1024]. gemm_sq: grid 512, K=4096.
    gemm_sq<<<dim3(64 * 8), 256, 0, stream>>>(h1, w2b, b2, nullptr,
                                              h2, 1024, 4096, 0, 8);
    // 7) out = LN(x1b + h2)  (fp32 out)
    ln_bf16_f32<<<8192, 256, 0, stream>>>(x1b, h2, ln2_g, ln2_b, out);
}